// Round 5
// baseline (177.878 us; speedup 1.0000x reference)
//
#include <hip/hip_runtime.h>

typedef unsigned short u16;
typedef unsigned int u32;
typedef __attribute__((ext_vector_type(8))) short short8;
typedef __attribute__((ext_vector_type(4))) float f32x4;

#define LOG2E 1.4426950408889634f
#define RSQRT_MD 0.04419417382415922f

__device__ __forceinline__ u16 f2bf(float f) {
  u32 u = __builtin_bit_cast(u32, f);
  u32 r = u + 0x7fffu + ((u >> 16) & 1u);
  return (u16)(r >> 16);
}

// ---------------- Kernel 1: weight prep ----------------
// blocks 0..23: wcat[192][512] via LDS transpose (coalesced both sides).
//   rows 0-63 Wq^T * (log2e/sqrt512), 64-127 Wk^T, 128-191 Wv^T.
// blocks 24..151: wot[512][64], wot[d][e] = sum_h Wo[h*64+e][d].
__global__ __launch_bounds__(256) void prep(
    const float* __restrict__ Wq, const float* __restrict__ Wk,
    const float* __restrict__ Wv, const float* __restrict__ Wo,
    u16* __restrict__ wcat, u16* __restrict__ wot) {
  __shared__ float ws[64 * 65];
  const int bid = blockIdx.x, t = threadIdx.x;
  if (bid < 24) {
    const int mat = bid >> 3, kc8 = bid & 7;
    const float* W = (mat == 0) ? Wq : ((mat == 1) ? Wk : Wv);
    const float scale = (mat == 0) ? (LOG2E * RSQRT_MD) : 1.0f;
#pragma unroll
    for (int i = 0; i < 16; ++i) {  // read W[k][n] coalesced (lanes vary n)
      int e = i * 256 + t;
      int k = e >> 6, n = e & 63;
      ws[k * 65 + n] = W[(size_t)(kc8 * 64 + k) * 64 + n] * scale;
    }
    __syncthreads();
#pragma unroll
    for (int i = 0; i < 16; ++i) {  // write wcat[n][k] coalesced (lanes vary k)
      int o = i * 256 + t;
      int n = o >> 6, k = o & 63;
      wcat[(size_t)(mat * 64 + n) * 512 + kc8 * 64 + k] = f2bf(ws[k * 65 + n]);
    }
  } else {
    int j = (bid - 24) * 256 + t;
    int d = j & 511, e = j >> 9;  // lanes vary d -> coalesced Wo reads
    float s = 0.f;
#pragma unroll
    for (int h = 0; h < 8; ++h) s += Wo[(size_t)(h * 64 + e) * 512 + d];
    wot[d * 64 + e] = f2bf(s);
  }
}

// ---------------- Kernel 2: QKV projection ----------------
// 512 threads = 8 waves: wave = (row-half rh, col-trio ct). 32-row tiles,
// grid 512. Single barrier; wcat B-frags direct from L2, K-loop unrolled x4.
__global__ __launch_bounds__(512, 4) void qkv_proj(
    const float* __restrict__ x, const u16* __restrict__ wcat,
    u16* __restrict__ Q, u16* __restrict__ K, u16* __restrict__ V) {
  __shared__ __align__(16) u16 xs[32 * 512];  // 32 KB, 16B-chunk swizzled
  const int t = threadIdx.x;
  const int lane = t & 63, wv = t >> 6;
  const int quad = lane >> 4, ml = lane & 15;
  const int rh = wv >> 2, ct = wv & 3;
  const int m0 = blockIdx.x * 32;
  const int cw = ct * 48;

#pragma unroll
  for (int i = 0; i < 8; ++i) {  // coalesced float4 staging, bf16 convert
    int f4 = i * 512 + t;
    int row = f4 >> 7, col4 = f4 & 127;
    float4 f = *(const float4*)&x[(size_t)(m0 + row) * 512 + col4 * 4];
    u32 lo = (u32)f2bf(f.x) | ((u32)f2bf(f.y) << 16);
    u32 hi = (u32)f2bf(f.z) | ((u32)f2bf(f.w) << 16);
    int ch = col4 >> 1, half = col4 & 1;
    *(uint2*)&xs[row * 512 + ((ch ^ (row & 7)) * 8) + half * 4] = make_uint2(lo, hi);
  }
  __syncthreads();  // full fence: staging (uint2) vs reads (short8) can't cross

  f32x4 acc[3];
#pragma unroll
  for (int j = 0; j < 3; ++j) acc[j] = (f32x4)0.0f;
  const int arow = rh * 16 + ml;

#pragma unroll 4
  for (int kc = 0; kc < 16; ++kc) {
    short8 a = *(const short8*)&xs[arow * 512 + (((kc * 4 + quad) ^ (ml & 7)) * 8)];
    short8 bf[3];
#pragma unroll
    for (int nt = 0; nt < 3; ++nt)
      bf[nt] = *(const short8*)&wcat[(size_t)(cw + nt * 16 + ml) * 512 + kc * 32 + quad * 8];
#pragma unroll
    for (int nt = 0; nt < 3; ++nt)
      acc[nt] = __builtin_amdgcn_mfma_f32_16x16x32_bf16(a, bf[nt], acc[nt], 0, 0, 0);
  }
  // epilogue: C rows = quad*4+r, cols = lane&15
  const int mrow = m0 + rh * 16 + quad * 4;
#pragma unroll
  for (int nt = 0; nt < 3; ++nt) {
    int n = cw + nt * 16 + ml;
    if (n < 128) {
      u16* dst = (n < 64) ? (Q + (size_t)mrow * 64 + n)
                          : (K + (size_t)mrow * 64 + (n - 64));
#pragma unroll
      for (int r = 0; r < 4; ++r) dst[(size_t)r * 64] = f2bf(acc[nt][r]);
    } else {
      int d = n - 128;
      int bb = m0 >> 11;
      int s0 = (m0 & 2047) + rh * 16 + quad * 4;
      ushort4 pk;
      pk.x = f2bf(acc[nt][0]);
      pk.y = f2bf(acc[nt][1]);
      pk.z = f2bf(acc[nt][2]);
      pk.w = f2bf(acc[nt][3]);
      *(ushort4*)&V[((size_t)(bb * 64 + d)) * 2048 + s0] = pk;
    }
  }
}

// ---------------- Kernel 3: flash attention + output projection ----------------
// Round-3-proven structure at 16 Q-rows/block, grid 1024 (batch-major mapping).
// 4 waves split keys 4x512; fixed-M softmax (M=0 safe: |scores|<=~1).
// ALL pt/zb round-trip accesses use uint-family types only (TBAA-safe).
__global__ __launch_bounds__(256) void attn_out(
    const u16* __restrict__ Q, const u16* __restrict__ K,
    const u16* __restrict__ VT, const u16* __restrict__ WoT,
    float* __restrict__ out) {
  __shared__ __align__(16) u16 pt[4][16 * 64];  // per-wave P^T staging
  __shared__ float zp[4][16][68];               // partial z^T [q][d]
  __shared__ float lp[4][16];
  __shared__ __align__(16) u16 zb[16 * 64];     // merged z [q][e] bf16 swizzled
  const int t = threadIdx.x, lane = t & 63, wv = t >> 6;
  const int quad = lane >> 4, ml = lane & 15;
  const int b = blockIdx.x >> 7;
  const int q0 = (blockIdx.x & 127) * 16;

  // Q fragments (B-operand: lane = q, elems = d)
  const u16* Qb = Q + ((size_t)(b * 2048 + q0)) * 64;
  short8 qf[2];
#pragma unroll
  for (int kc = 0; kc < 2; ++kc)
    qf[kc] = *(const short8*)&Qb[ml * 64 + kc * 32 + quad * 8];

  f32x4 z[4];
#pragma unroll
  for (int j = 0; j < 4; ++j) z[j] = (f32x4)0.0f;
  f32x4 ls = (f32x4)0.0f;

  const u16* Kb = K + ((size_t)(b * 2048 + wv * 512)) * 64;
  const u16* Vb = VT + ((size_t)(b * 64)) * 2048 + wv * 512;

  for (int it = 0; it < 8; ++it) {
    // K fragments (A-operand: lane = key, elems = d)
    short8 kbl[2][4];
#pragma unroll
    for (int kc = 0; kc < 2; ++kc)
#pragma unroll
      for (int g = 0; g < 4; ++g)
        kbl[kc][g] = *(const short8*)&Kb[(size_t)(it * 64 + g * 16 + ml) * 64 + kc * 32 + quad * 8];
    // V^T fragments (A-operand of PV: lane = d, elems = key)
    short8 vb[2][4];
#pragma unroll
    for (int kc = 0; kc < 2; ++kc)
#pragma unroll
      for (int nt = 0; nt < 4; ++nt)
        vb[kc][nt] = *(const short8*)&Vb[(size_t)(nt * 16 + ml) * 2048 + it * 64 + kc * 32 + quad * 8];
    // S^T = K @ Q^T
    f32x4 sc[4];
#pragma unroll
    for (int g = 0; g < 4; ++g) sc[g] = (f32x4)0.0f;
#pragma unroll
    for (int kc = 0; kc < 2; ++kc)
#pragma unroll
      for (int g = 0; g < 4; ++g)
        sc[g] = __builtin_amdgcn_mfma_f32_16x16x32_bf16(kbl[kc][g], qf[kc], sc[g], 0, 0, 0);
    // P = exp2(S^T); pack keys g*16+quad*4..+3 -> 8B write (round-3 pattern)
#pragma unroll
    for (int g = 0; g < 4; ++g) {
#pragma unroll
      for (int r = 0; r < 4; ++r) sc[g][r] = __builtin_amdgcn_exp2f(sc[g][r]);
      ls = ls + sc[g];
      u32 lo = (u32)f2bf(sc[g][0]) | ((u32)f2bf(sc[g][1]) << 16);
      u32 hi = (u32)f2bf(sc[g][2]) | ((u32)f2bf(sc[g][3]) << 16);
      int ch = g * 2 + (quad >> 1);
      *(uint2*)&pt[wv][ml * 64 + ((ch ^ (ml & 7)) * 8) + (quad & 1) * 4] = make_uint2(lo, hi);
    }
    // PV: z^T += V^T @ P^T ; read whole 16B chunk as uint4 (same TBAA family
    // as the uint2 writes -> compiler cannot reorder across the dependency)
#pragma unroll
    for (int kc = 0; kc < 2; ++kc) {
      uint4 praw = *(const uint4*)&pt[wv][ml * 64 + (((kc * 4 + quad) ^ (ml & 7)) * 8)];
      short8 pa = __builtin_bit_cast(short8, praw);
#pragma unroll
      for (int nt = 0; nt < 4; ++nt)
        z[nt] = __builtin_amdgcn_mfma_f32_16x16x32_bf16(vb[kc][nt], pa, z[nt], 0, 0, 0);
    }
  }
  // per-wave l reduce: 4 comps + across quads (lanes ml, ml+16, ml+32, ml+48)
  {
    float l = ls[0] + ls[1] + ls[2] + ls[3];
    l += __shfl_xor(l, 16);
    l += __shfl_xor(l, 32);
    if (quad == 0) lp[wv][ml] = l;
  }
  // partial z^T: zp[wv][q=ml][d], d = nt*16+quad*4+r
#pragma unroll
  for (int nt = 0; nt < 4; ++nt)
#pragma unroll
    for (int r = 0; r < 4; ++r)
      zp[wv][ml][nt * 16 + quad * 4 + r] = z[nt][r];
  __syncthreads();
  {  // merge: plain sum (fixed M); thread: q = t>>4, d-group dgrp = t&15 (4 d's)
    int q = t >> 4, dgrp = t & 15;
    float L = lp[0][q] + lp[1][q] + lp[2][q] + lp[3][q];
    float rl = 1.0f / L;
    f32x4 a = (f32x4)0.0f;
#pragma unroll
    for (int w = 0; w < 4; ++w) a = a + *(const f32x4*)&zp[w][q][dgrp * 4];
    u32 lo = (u32)f2bf(a[0] * rl) | ((u32)f2bf(a[1] * rl) << 16);
    u32 hi = (u32)f2bf(a[2] * rl) | ((u32)f2bf(a[3] * rl) << 16);
    *(uint2*)&zb[q * 64 + (((dgrp >> 1) ^ (q & 7)) * 8) + (dgrp & 1) * 4] = make_uint2(lo, hi);
  }
  __syncthreads();
  // out^T = WoSum^T @ z^T : A = WoT frag (lane = out-col), B = z frag (lane = q)
  short8 zf[2];
#pragma unroll
  for (int kc = 0; kc < 2; ++kc) {
    uint4 zraw = *(const uint4*)&zb[ml * 64 + (((kc * 4 + quad) ^ (ml & 7)) * 8)];
    zf[kc] = __builtin_bit_cast(short8, zraw);
  }
  const size_t ob = (size_t)(b * 2048 + q0);
#pragma unroll
  for (int nt2 = 0; nt2 < 8; ++nt2) {
    int col0 = wv * 128 + nt2 * 16;
    short8 wb0 = *(const short8*)&WoT[(size_t)(col0 + ml) * 64 + quad * 8];
    short8 wb1 = *(const short8*)&WoT[(size_t)(col0 + ml) * 64 + 32 + quad * 8];
    f32x4 o = (f32x4)0.0f;
    o = __builtin_amdgcn_mfma_f32_16x16x32_bf16(wb0, zf[0], o, 0, 0, 0);
    o = __builtin_amdgcn_mfma_f32_16x16x32_bf16(wb1, zf[1], o, 0, 0, 0);
    float4 st;
    st.x = o[0]; st.y = o[1]; st.z = o[2]; st.w = o[3];
    *(float4*)&out[(ob + ml) * 512 + col0 + quad * 4] = st;
  }
}

extern "C" void kernel_launch(void* const* d_in, const int* in_sizes, int n_in,
                              void* d_out, int out_size, void* d_ws, size_t ws_size,
                              hipStream_t stream) {
  const float* x = (const float*)d_in[0];
  const float* Wq = (const float*)d_in[1];
  const float* Wk = (const float*)d_in[2];
  const float* Wv = (const float*)d_in[3];
  const float* Wo = (const float*)d_in[4];
  float* out = (float*)d_out;

  u16* wcat = (u16*)d_ws;          // [192][512]
  u16* wot = wcat + 192 * 512;     // [512][64]
  u16* Q = wot + 512 * 64;         // [16384][64]
  u16* K = Q + 16384 * 64;         // [16384][64]
  u16* V = K + 16384 * 64;         // [8][64][2048] (V^T per batch)

  hipLaunchKernelGGL(prep, dim3(152), dim3(256), 0, stream, Wq, Wk, Wv, Wo, wcat, wot);
  hipLaunchKernelGGL(qkv_proj, dim3(512), dim3(512), 0, stream, x, wcat, Q, K, V);
  hipLaunchKernelGGL(attn_out, dim3(1024), dim3(256), 0, stream, Q, K, V, wot, out);
}

// Round 6
// 148.987 us; speedup vs baseline: 1.1939x; 1.1939x over previous
//
#include <hip/hip_runtime.h>

typedef unsigned short u16;
typedef unsigned int u32;
typedef __attribute__((ext_vector_type(8))) short short8;
typedef __attribute__((ext_vector_type(4))) float f32x4;

#define LOG2E 1.4426950408889634f
#define RSQRT_MD 0.04419417382415922f

__device__ __forceinline__ u16 f2bf(float f) {
  u32 u = __builtin_bit_cast(u32, f);
  u32 r = u + 0x7fffu + ((u >> 16) & 1u);
  return (u16)(r >> 16);
}

// ---------------- Kernel 1: weight prep ----------------
// blocks 0..23: wcat[192][512] via LDS transpose (coalesced both sides).
//   rows 0-63 Wq^T * (log2e/sqrt512), 64-127 Wk^T, 128-191 Wv^T.
// blocks 24..151: wot[512][64], wot[d][e] = sum_h Wo[h*64+e][d].
__global__ __launch_bounds__(256) void prep(
    const float* __restrict__ Wq, const float* __restrict__ Wk,
    const float* __restrict__ Wv, const float* __restrict__ Wo,
    u16* __restrict__ wcat, u16* __restrict__ wot) {
  __shared__ float ws[64 * 65];
  const int bid = blockIdx.x, t = threadIdx.x;
  if (bid < 24) {
    const int mat = bid >> 3, kc8 = bid & 7;
    const float* W = (mat == 0) ? Wq : ((mat == 1) ? Wk : Wv);
    const float scale = (mat == 0) ? (LOG2E * RSQRT_MD) : 1.0f;
#pragma unroll
    for (int i = 0; i < 16; ++i) {  // read W[k][n] coalesced (lanes vary n)
      int e = i * 256 + t;
      int k = e >> 6, n = e & 63;
      ws[k * 65 + n] = W[(size_t)(kc8 * 64 + k) * 64 + n] * scale;
    }
    __syncthreads();
#pragma unroll
    for (int i = 0; i < 16; ++i) {  // write wcat[n][k] coalesced (lanes vary k)
      int o = i * 256 + t;
      int n = o >> 6, k = o & 63;
      wcat[(size_t)(mat * 64 + n) * 512 + kc8 * 64 + k] = f2bf(ws[k * 65 + n]);
    }
  } else {
    int j = (bid - 24) * 256 + t;
    int d = j & 511, e = j >> 9;  // lanes vary d -> coalesced Wo reads
    float s = 0.f;
#pragma unroll
    for (int h = 0; h < 8; ++h) s += Wo[(size_t)(h * 64 + e) * 512 + d];
    wot[d * 64 + e] = f2bf(s);
  }
}

// ---------------- Kernel 2: QKV projection ----------------
// 512 threads = 8 waves: wave = (row-half rh, col-trio ct). 32-row tiles,
// grid 512. Single barrier; wcat B-frags direct from L2, K-loop unrolled x4.
__global__ __launch_bounds__(512, 4) void qkv_proj(
    const float* __restrict__ x, const u16* __restrict__ wcat,
    u16* __restrict__ Q, u16* __restrict__ K, u16* __restrict__ V) {
  __shared__ __align__(16) u16 xs[32 * 512];  // 32 KB, 16B-chunk swizzled
  const int t = threadIdx.x;
  const int lane = t & 63, wv = t >> 6;
  const int quad = lane >> 4, ml = lane & 15;
  const int rh = wv >> 2, ct = wv & 3;
  const int m0 = blockIdx.x * 32;
  const int cw = ct * 48;

#pragma unroll
  for (int i = 0; i < 8; ++i) {  // coalesced float4 staging, bf16 convert
    int f4 = i * 512 + t;
    int row = f4 >> 7, col4 = f4 & 127;
    float4 f = *(const float4*)&x[(size_t)(m0 + row) * 512 + col4 * 4];
    u32 lo = (u32)f2bf(f.x) | ((u32)f2bf(f.y) << 16);
    u32 hi = (u32)f2bf(f.z) | ((u32)f2bf(f.w) << 16);
    int ch = col4 >> 1, half = col4 & 1;
    *(uint2*)&xs[row * 512 + ((ch ^ (row & 7)) * 8) + half * 4] = make_uint2(lo, hi);
  }
  __syncthreads();

  f32x4 acc[3];
#pragma unroll
  for (int j = 0; j < 3; ++j) acc[j] = (f32x4)0.0f;
  const int arow = rh * 16 + ml;

#pragma unroll 4
  for (int kc = 0; kc < 16; ++kc) {
    uint4 araw = *(const uint4*)&xs[arow * 512 + (((kc * 4 + quad) ^ (ml & 7)) * 8)];
    short8 a = __builtin_bit_cast(short8, araw);
    short8 bf[3];
#pragma unroll
    for (int nt = 0; nt < 3; ++nt)
      bf[nt] = *(const short8*)&wcat[(size_t)(cw + nt * 16 + ml) * 512 + kc * 32 + quad * 8];
#pragma unroll
    for (int nt = 0; nt < 3; ++nt)
      acc[nt] = __builtin_amdgcn_mfma_f32_16x16x32_bf16(a, bf[nt], acc[nt], 0, 0, 0);
  }
  // epilogue: C rows = quad*4+r, cols = lane&15
  const int mrow = m0 + rh * 16 + quad * 4;
#pragma unroll
  for (int nt = 0; nt < 3; ++nt) {
    int n = cw + nt * 16 + ml;
    if (n < 128) {
      u16* dst = (n < 64) ? (Q + (size_t)mrow * 64 + n)
                          : (K + (size_t)mrow * 64 + (n - 64));
#pragma unroll
      for (int r = 0; r < 4; ++r) dst[(size_t)r * 64] = f2bf(acc[nt][r]);
    } else {
      int d = n - 128;
      int bb = m0 >> 11;
      int s0 = (m0 & 2047) + rh * 16 + quad * 4;
      ushort4 pk;
      pk.x = f2bf(acc[nt][0]);
      pk.y = f2bf(acc[nt][1]);
      pk.z = f2bf(acc[nt][2]);
      pk.w = f2bf(acc[nt][3]);
      *(ushort4*)&V[((size_t)(bb * 64 + d)) * 2048 + s0] = pk;
    }
  }
}

// ---------------- Kernel 3: flash attention + output projection ----------------
// 32 Q-rows/block (2 subs/wave), 4 waves split keys 4x512, grid 512.
// batch = blockIdx&7 -> all blocks of a batch land on one XCD (round-robin
// dispatch heuristic): that XCD's L2 caches the batch's entire K+V (512 KB),
// so the redundant fragment re-reads stream from LOCAL L2, not L3.
// Fixed-M softmax (M=0 safe: |scores|<=~1). All pt/zb round-trips uint-family.
__global__ __launch_bounds__(256) void attn_out(
    const u16* __restrict__ Q, const u16* __restrict__ K,
    const u16* __restrict__ VT, const u16* __restrict__ WoT,
    float* __restrict__ out) {
  __shared__ __align__(16) u16 pt[4][2][16 * 64];  // [wave][sub] P^T staging
  __shared__ float zp[4][32 * 66];                 // [wave] partial z [q][d]
  __shared__ float lp[4][32];
  __shared__ __align__(16) u16 zb[32 * 64];        // merged z [q][e] swizzled
  const int t = threadIdx.x, lane = t & 63, wv = t >> 6;
  const int quad = lane >> 4, ml = lane & 15;
  const int b = blockIdx.x & 7;          // batch -> XCD pin
  const int q0 = (blockIdx.x >> 3) * 32; // 64 q-tiles per batch

  // Q fragments (B-operand: lane = q, elems = d)
  const u16* Qb = Q + ((size_t)(b * 2048 + q0)) * 64;
  short8 qf[2][2];
#pragma unroll
  for (int sub = 0; sub < 2; ++sub)
#pragma unroll
    for (int kc = 0; kc < 2; ++kc)
      qf[sub][kc] = *(const short8*)&Qb[(sub * 16 + ml) * 64 + kc * 32 + quad * 8];

  f32x4 z[2][4];
#pragma unroll
  for (int i = 0; i < 2; ++i)
#pragma unroll
    for (int j = 0; j < 4; ++j) z[i][j] = (f32x4)0.0f;
  f32x4 ls[2];
  ls[0] = (f32x4)0.0f;
  ls[1] = (f32x4)0.0f;

  const u16* Kb = K + ((size_t)(b * 2048 + wv * 512)) * 64;
  const u16* Vb = VT + ((size_t)(b * 64)) * 2048 + wv * 512;

  for (int it = 0; it < 8; ++it) {
    // K fragments (A-operand: lane = key, elems = d) — shared by both subs
    short8 kbl[2][4];
#pragma unroll
    for (int kc = 0; kc < 2; ++kc)
#pragma unroll
      for (int g = 0; g < 4; ++g)
        kbl[kc][g] = *(const short8*)&Kb[(size_t)(it * 64 + g * 16 + ml) * 64 + kc * 32 + quad * 8];
    // V^T fragments (A-operand of PV: lane = d, elems = key) — shared
    short8 vb[2][4];
#pragma unroll
    for (int kc = 0; kc < 2; ++kc)
#pragma unroll
      for (int nt = 0; nt < 4; ++nt)
        vb[kc][nt] = *(const short8*)&Vb[(size_t)(nt * 16 + ml) * 2048 + it * 64 + kc * 32 + quad * 8];
    // S^T = K @ Q^T, both subs
    f32x4 sc[2][4];
#pragma unroll
    for (int i = 0; i < 2; ++i)
#pragma unroll
      for (int j = 0; j < 4; ++j) sc[i][j] = (f32x4)0.0f;
#pragma unroll
    for (int kc = 0; kc < 2; ++kc)
#pragma unroll
      for (int sub = 0; sub < 2; ++sub)
#pragma unroll
        for (int g = 0; g < 4; ++g)
          sc[sub][g] = __builtin_amdgcn_mfma_f32_16x16x32_bf16(kbl[kc][g], qf[sub][kc], sc[sub][g], 0, 0, 0);
    // P = exp2(S^T): write BOTH subs first (write->read latency overlaps)
#pragma unroll
    for (int sub = 0; sub < 2; ++sub)
#pragma unroll
      for (int g = 0; g < 4; ++g) {
#pragma unroll
        for (int r = 0; r < 4; ++r) sc[sub][g][r] = __builtin_amdgcn_exp2f(sc[sub][g][r]);
        ls[sub] = ls[sub] + sc[sub][g];
        u32 lo = (u32)f2bf(sc[sub][g][0]) | ((u32)f2bf(sc[sub][g][1]) << 16);
        u32 hi = (u32)f2bf(sc[sub][g][2]) | ((u32)f2bf(sc[sub][g][3]) << 16);
        int ch = g * 2 + (quad >> 1);
        *(uint2*)&pt[wv][sub][ml * 64 + ((ch ^ (ml & 7)) * 8) + (quad & 1) * 4] = make_uint2(lo, hi);
      }
    // PV: z^T += V^T @ P^T (uint4 reads — same TBAA family as writes)
#pragma unroll
    for (int sub = 0; sub < 2; ++sub)
#pragma unroll
      for (int kc = 0; kc < 2; ++kc) {
        uint4 praw = *(const uint4*)&pt[wv][sub][ml * 64 + (((kc * 4 + quad) ^ (ml & 7)) * 8)];
        short8 pa = __builtin_bit_cast(short8, praw);
#pragma unroll
        for (int nt = 0; nt < 4; ++nt)
          z[sub][nt] = __builtin_amdgcn_mfma_f32_16x16x32_bf16(vb[kc][nt], pa, z[sub][nt], 0, 0, 0);
      }
  }
  // per-wave l reduce: 4 comps + across quads (lanes ml, ml+16, ml+32, ml+48)
#pragma unroll
  for (int sub = 0; sub < 2; ++sub) {
    float l = ls[sub][0] + ls[sub][1] + ls[sub][2] + ls[sub][3];
    l += __shfl_xor(l, 16);
    l += __shfl_xor(l, 32);
    if (quad == 0) lp[wv][sub * 16 + ml] = l;
  }
  // partial z^T: zp[wv][q][d], q = sub*16+ml, d = nt*16+quad*4+r (f32x4 over r)
#pragma unroll
  for (int sub = 0; sub < 2; ++sub)
#pragma unroll
    for (int nt = 0; nt < 4; ++nt)
      *(f32x4*)&zp[wv][(sub * 16 + ml) * 66 + nt * 16 + quad * 4] = z[sub][nt];
  __syncthreads();
  {  // merge: plain sum (fixed M); thread: q = t>>3 (32), dgrp = t&7 (8 d's)
    int q = t >> 3, dgrp = t & 7;
    float L = lp[0][q] + lp[1][q] + lp[2][q] + lp[3][q];
    float rl = 1.0f / L;
    f32x4 a0 = (f32x4)0.0f, a1 = (f32x4)0.0f;
#pragma unroll
    for (int w = 0; w < 4; ++w) {
      a0 = a0 + *(const f32x4*)&zp[w][q * 66 + dgrp * 8];
      a1 = a1 + *(const f32x4*)&zp[w][q * 66 + dgrp * 8 + 4];
    }
    uint4 pk;
    pk.x = (u32)f2bf(a0[0] * rl) | ((u32)f2bf(a0[1] * rl) << 16);
    pk.y = (u32)f2bf(a0[2] * rl) | ((u32)f2bf(a0[3] * rl) << 16);
    pk.z = (u32)f2bf(a1[0] * rl) | ((u32)f2bf(a1[1] * rl) << 16);
    pk.w = (u32)f2bf(a1[2] * rl) | ((u32)f2bf(a1[3] * rl) << 16);
    *(uint4*)&zb[q * 64 + ((dgrp ^ (q & 7)) * 8)] = pk;
  }
  __syncthreads();
  // out^T = WoSum^T @ z^T : A = WoT frag (lane = out-col), B = z frag (lane = q)
  short8 zf[2][2];
#pragma unroll
  for (int sub = 0; sub < 2; ++sub)
#pragma unroll
    for (int kc = 0; kc < 2; ++kc) {
      uint4 zraw = *(const uint4*)&zb[(sub * 16 + ml) * 64 + (((kc * 4 + quad) ^ (ml & 7)) * 8)];
      zf[sub][kc] = __builtin_bit_cast(short8, zraw);
    }
  const size_t ob = (size_t)(b * 2048 + q0);
#pragma unroll
  for (int nt2 = 0; nt2 < 8; ++nt2) {
    int col0 = wv * 128 + nt2 * 16;
    short8 wb0 = *(const short8*)&WoT[(size_t)(col0 + ml) * 64 + quad * 8];
    short8 wb1 = *(const short8*)&WoT[(size_t)(col0 + ml) * 64 + 32 + quad * 8];
#pragma unroll
    for (int sub = 0; sub < 2; ++sub) {
      f32x4 o = (f32x4)0.0f;
      o = __builtin_amdgcn_mfma_f32_16x16x32_bf16(wb0, zf[sub][0], o, 0, 0, 0);
      o = __builtin_amdgcn_mfma_f32_16x16x32_bf16(wb1, zf[sub][1], o, 0, 0, 0);
      float4 st;
      st.x = o[0]; st.y = o[1]; st.z = o[2]; st.w = o[3];
      *(float4*)&out[(ob + sub * 16 + ml) * 512 + col0 + quad * 4] = st;
    }
  }
}

extern "C" void kernel_launch(void* const* d_in, const int* in_sizes, int n_in,
                              void* d_out, int out_size, void* d_ws, size_t ws_size,
                              hipStream_t stream) {
  const float* x = (const float*)d_in[0];
  const float* Wq = (const float*)d_in[1];
  const float* Wk = (const float*)d_in[2];
  const float* Wv = (const float*)d_in[3];
  const float* Wo = (const float*)d_in[4];
  float* out = (float*)d_out;

  u16* wcat = (u16*)d_ws;          // [192][512]
  u16* wot = wcat + 192 * 512;     // [512][64]
  u16* Q = wot + 512 * 64;         // [16384][64]
  u16* K = Q + 16384 * 64;         // [16384][64]
  u16* V = K + 16384 * 64;         // [8][64][2048] (V^T per batch)

  hipLaunchKernelGGL(prep, dim3(152), dim3(256), 0, stream, Wq, Wk, Wv, Wo, wcat, wot);
  hipLaunchKernelGGL(qkv_proj, dim3(512), dim3(512), 0, stream, x, wcat, Q, K, V);
  hipLaunchKernelGGL(attn_out, dim3(512), dim3(256), 0, stream, Q, K, V, wot, out);
}